// Round 12
// baseline (298.324 us; speedup 1.0000x reference)
//
#include <hip/hip_runtime.h>
#include <hip/hip_bf16.h>

// B=32, Q=16, F=4096, E=256, NL=8, L=2 residual layers per mapper.
#define B_   32
#define Q_   16
#define F_   4096
#define E_   256
#define NL_  8
#define FT   64     // feature rows per chunk
#define NTB  8      // row-tiles per batch (512 rows each)
#define CH   8      // chunks per tile (NTB*CH*FT == F_)
#define TPB  1024   // 16 waves

typedef __attribute__((ext_vector_type(8))) __bf16 bf16x8_t;
typedef __attribute__((ext_vector_type(4))) __bf16 bf16x4_t;
typedef __attribute__((ext_vector_type(4))) float  f32x4;

// ---- LDS swizzle for [64][256] bf16 tiles (row stride 512 B) ----
__device__ __forceinline__ int swz(int r) {
  return ((r & 7) << 4) ^ (((r >> 3) & 3) << 5);
}
__device__ __forceinline__ int xoff(int r, int c2) {  // c2 = byte offset in row [0,512)
  return r * 512 + (c2 ^ swz(r));
}
__device__ __forceinline__ unsigned short f2bf_bits(float f) {
  __bf16 h = (__bf16)f;
  return __builtin_bit_cast(unsigned short, h);
}

// ---------------- prep: coalesced tiled transposes (8 mats, all bf16) -------
__global__ __launch_bounds__(256) void prep_kernel(
    const float* __restrict__ Wf, const float* __restrict__ Wv,
    const float* __restrict__ Wq, const float* __restrict__ Wc,
    unsigned short* __restrict__ WtF, unsigned short* __restrict__ WtV,
    unsigned short* __restrict__ WqT, unsigned short* __restrict__ WcT) {
  const int blk = blockIdx.x;
  const int t = threadIdx.x;
  __shared__ float ts[64][65];
  const int mat = blk >> 4;
  const int t16 = blk & 15;
  const int k0 = (t16 >> 2) * 64, n0 = (t16 & 3) * 64;
  const float* src;
  if (mat < 2) src = Wf + mat * 65536;
  else if (mat < 4) src = Wv + (mat - 2) * 65536;
  else if (mat < 6) src = Wq + (mat - 4) * 65536;
  else src = Wc + (mat - 6) * 65536;
#pragma unroll
  for (int p = 0; p < 16; ++p) {
    int e = p * 256 + t;
    int kk = e >> 6, nn = e & 63;
    ts[nn][kk] = src[(k0 + kk) * 256 + n0 + nn];   // coalesced in nn
  }
  __syncthreads();
  unsigned short* dst;
  if (mat < 2) dst = WtF + mat * 65536;
  else if (mat < 4) dst = WtV + (mat - 2) * 65536;
  else if (mat < 6) dst = WqT + (mat - 4) * 65536;
  else dst = WcT + (mat - 6) * 65536;
#pragma unroll
  for (int p = 0; p < 16; ++p) {
    int e = p * 256 + t;
    int nn = e >> 6, kk = e & 63;
    dst[(n0 + nn) * 256 + k0 + kk] = f2bf_bits(ts[nn][kk]);  // coalesced in kk
  }
}

// ---------------- register staging (T14: issue early, write late) -----------
struct StageRegs { f32x4 v[4]; };   // 16 VGPRs while live; statically indexed

__device__ __forceinline__ void stage_issue(StageRegs& s, const float* __restrict__ src, int tid) {
#pragma unroll
  for (int j = 0; j < 2; ++j) {
    int u = j * 1024 + tid;                // 16B-out-unit id (2048 per 64-row tile)
    int r = u >> 5;
    int c8 = (u & 31) << 3;
    const f32x4* p = (const f32x4*)(src + (size_t)r * E_ + c8);
    s.v[2 * j]     = __builtin_nontemporal_load(p);
    s.v[2 * j + 1] = __builtin_nontemporal_load(p + 1);
  }
}
__device__ __forceinline__ void stage_write(const StageRegs& s, char* Xs, int tid) {
#pragma unroll
  for (int j = 0; j < 2; ++j) {
    int u = j * 1024 + tid;
    int r = u >> 5;
    int cb = (u & 31) << 4;
    f32x4 a = s.v[2 * j], b = s.v[2 * j + 1];
    bf16x8_t o;
    o[0] = (__bf16)a[0]; o[1] = (__bf16)a[1]; o[2] = (__bf16)a[2]; o[3] = (__bf16)a[3];
    o[4] = (__bf16)b[0]; o[5] = (__bf16)b[1]; o[6] = (__bf16)b[2]; o[7] = (__bf16)b[3];
    *(bf16x8_t*)(Xs + xoff(r, cb)) = o;
  }
}

// ---- Persistent per-wave weight fragments: 16 e-rows x 256 k (8 KB) --------
struct WFrag { bf16x8_t w[8]; };   // 32 VGPRs

__device__ __forceinline__ void load_wfrag(WFrag& f, const unsigned short* __restrict__ Wt,
                                           int w, int lane) {
  const int c16 = lane & 15, kb = (lane >> 4) << 3;
  const unsigned short* r0 = Wt + (w * 16 + c16) * E_ + kb;
#pragma unroll
  for (int ks = 0; ks < 8; ++ks) f.w[ks] = *(const bf16x8_t*)(r0 + ks * 32);
}

// ---- Ping-pong residual layer, resident weights. Read Xin, write Xout. -----
// One barrier (at end). Wave w owns e in [w*16, w*16+16). D[e][m].
__device__ __forceinline__ void layer_res(const char* __restrict__ Xin, char* __restrict__ Xout,
                                          const WFrag& wf, const float* __restrict__ bias_base,
                                          int w, int lane) {
  const int c16 = lane & 15, g = lane >> 4, kb = g << 3;
  f32x4 acc[4];
#pragma unroll
  for (int mf = 0; mf < 4; ++mf) acc[mf] = (f32x4){0.f, 0.f, 0.f, 0.f};

#pragma unroll
  for (int ks = 0; ks < 8; ++ks) {
    const int k = ks * 32 + kb;
#pragma unroll
    for (int mf = 0; mf < 4; ++mf) {
      bf16x8_t xb = *(const bf16x8_t*)(Xin + xoff(mf * 16 + c16, k << 1));
      acc[mf] = __builtin_amdgcn_mfma_f32_16x16x32_bf16(wf.w[ks], xb, acc[mf], 0, 0, 0);
    }
  }
  const int e0 = w * 16 + (g << 2);
  const float4 b4 = *(const float4*)(bias_base + e0);
#pragma unroll
  for (int mf = 0; mf < 4; ++mf) {
    const int m = mf * 16 + c16;
    bf16x4_t old = *(const bf16x4_t*)(Xin + xoff(m, e0 << 1));
    bf16x4_t nw;
    nw[0] = (__bf16)(fmaxf(acc[mf][0] + b4.x, 0.f) + (float)old[0]);
    nw[1] = (__bf16)(fmaxf(acc[mf][1] + b4.y, 0.f) + (float)old[1]);
    nw[2] = (__bf16)(fmaxf(acc[mf][2] + b4.z, 0.f) + (float)old[2]);
    nw[3] = (__bf16)(fmaxf(acc[mf][3] + b4.w, 0.f) + (float)old[3]);
    *(bf16x4_t*)(Xout + xoff(m, e0 << 1)) = nw;
  }
  __syncthreads();
}

// ---------------- q-mapper via MFMA: 512 rows = B*Q, 8 blocks ---------------
__global__ __launch_bounds__(TPB) __attribute__((amdgpu_waves_per_eu(4, 4)))
void qmap_kernel(
    const float* __restrict__ query, const unsigned short* __restrict__ WqT,
    const float* __restrict__ bq, unsigned short* __restrict__ qmb) {
  const int blk = blockIdx.x;                 // rows [blk*64, blk*64+64)
  const int tid = threadIdx.x;
  const int lane = tid & 63, w = tid >> 6;

  __shared__ __align__(128) char X[32768];
  __shared__ __align__(128) char Xt[32768];

  WFrag wf1, wf2;
  load_wfrag(wf1, WqT, w, lane);
  load_wfrag(wf2, WqT + 65536, w, lane);

  StageRegs s;
  stage_issue(s, query + (size_t)blk * 64 * E_, tid);
  stage_write(s, X, tid);
  __syncthreads();

  layer_res(X, Xt, wf1, bq, w, lane);
  layer_res(Xt, X, wf2, bq + E_, w, lane);

#pragma unroll
  for (int j = 0; j < 2; ++j) {
    int u = j * 1024 + tid;
    int r = u >> 5;
    bf16x8_t v = *(const bf16x8_t*)(X + xoff(r, (u & 31) << 4));
    *(bf16x8_t*)(qmb + (size_t)(blk * 64 + r) * E_ + ((u & 31) << 3)) = v;
  }
}

// ---------------- pass A: features -> f-mapper -> S -> Ws -------------------
__global__ __launch_bounds__(TPB) __attribute__((amdgpu_waves_per_eu(4, 4)))
void passA_kernel(
    const float* __restrict__ features,
    const float* __restrict__ amask, const float* __restrict__ ftw,
    const unsigned short* __restrict__ WtF, const float* __restrict__ bfb,
    const unsigned short* __restrict__ qmb, unsigned short* __restrict__ Wsg) {
  const int bid0 = blockIdx.x;
  const int bid = (bid0 & 7) * 32 + (bid0 >> 3);   // XCD swizzle (256 = 8*32)
  const int b = bid >> 3, tb = bid & 7;
  const int tid = threadIdx.x;
  const int lane = tid & 63, w = tid >> 6;
  const int c16 = lane & 15, g = lane >> 4, kb = g << 3;

  __shared__ __align__(128) char X[2][32768];
  __shared__ __align__(128) char Xt[32768];

  WFrag wf1, wf2;
  load_wfrag(wf1, WtF, w, lane);
  load_wfrag(wf2, WtF + 65536, w, lane);

  const float* srcB = features + (size_t)(b * F_ + tb * CH * FT) * E_;

  StageRegs s;
  stage_issue(s, srcB, tid);
  stage_write(s, X[0], tid);
  __syncthreads();
  int cur = 0;

  for (int c = 0; c < CH; ++c) {
    if (c + 1 < CH) stage_issue(s, srcB + (size_t)(c + 1) * FT * E_, tid);

    layer_res(X[cur], Xt, wf1, bfb, w, lane);          // barrier inside
    layer_res(Xt, X[cur], wf2, bfb + E_, w, lane);     // barrier inside

    if (c + 1 < CH) stage_write(s, X[cur ^ 1], tid);

    // ---- S = qm @ Fm^T (waves 0-3; wave w owns f rows [w*16, w*16+16)) ----
    if (w < 4) {
      const int f0 = (tb * CH + c) * FT;
      f32x4 sv = (f32x4){0.f, 0.f, 0.f, 0.f};
      const int fl = w * 16 + c16;
      const unsigned short* qbase = qmb + (size_t)(b * Q_ + c16) * E_ + kb;
#pragma unroll
      for (int ks = 0; ks < 8; ++ks) {
        bf16x8_t qa = *(const bf16x8_t*)(qbase + ks * 32);
        bf16x8_t xb = *(const bf16x8_t*)(X[cur] + xoff(fl, (ks * 32 + kb) << 1));
        sv = __builtin_amdgcn_mfma_f32_16x16x32_bf16(qa, xb, sv, 0, 0, 0);
      }
      const int fg = f0 + fl;
      const float lw = ftw[b * F_ + fg] * amask[b * F_ + fg];
#pragma unroll
      for (int r = 0; r < 4; ++r) {
        float sg = 1.f / (1.f + __expf(-sv[r]));
        Wsg[((size_t)(b * Q_ + g * 4 + r)) * F_ + fg] = f2bf_bits(sg * lw);
      }
    }
    __syncthreads();                       // staging + S complete
    cur ^= 1;
  }
}

// ---------------- pass B: values -> v-mapper -> PV -> partials --------------
__global__ __launch_bounds__(TPB) __attribute__((amdgpu_waves_per_eu(4, 4)))
void passB_kernel(
    const float* __restrict__ values,
    const unsigned short* __restrict__ WtV, const float* __restrict__ bvb,
    const unsigned short* __restrict__ Wsg, float* __restrict__ partials) {
  const int bid0 = blockIdx.x;
  const int bid = (bid0 & 7) * 32 + (bid0 >> 3);
  const int b = bid >> 3, tb = bid & 7;
  const int tid = threadIdx.x;
  const int lane = tid & 63, w = tid >> 6;
  const int c16 = lane & 15, g = lane >> 4, kb = g << 3;

  __shared__ __align__(128) char X[2][32768];
  __shared__ __align__(128) char Xt[32768];
  __shared__ __align__(16) unsigned short Wl[Q_][FT + 8];

  WFrag wf1, wf2;
  load_wfrag(wf1, WtV, w, lane);
  load_wfrag(wf2, WtV + 65536, w, lane);

  const float* srcB = values + (size_t)(b * F_ + tb * CH * FT) * E_;

  f32x4 pacc = (f32x4){0.f, 0.f, 0.f, 0.f};

  StageRegs s;
  stage_issue(s, srcB, tid);
  stage_write(s, X[0], tid);
  __syncthreads();
  int cur = 0;

  for (int c = 0; c < CH; ++c) {
    const int f0 = (tb * CH + c) * FT;
    if (c + 1 < CH) stage_issue(s, srcB + (size_t)(c + 1) * FT * E_, tid);

    layer_res(X[cur], Xt, wf1, bvb, w, lane);          // barrier inside

    // attn weights for this chunk (ordered before PV by layer2's barrier)
    {
      int q = tid >> 6, j = tid & 63;     // 1024 = 16 q x 64 f
      Wl[q][j] = Wsg[((size_t)(b * Q_ + q)) * F_ + f0 + j];
    }

    layer_res(Xt, X[cur], wf2, bvb + E_, w, lane);     // barrier inside

    if (c + 1 < CH) stage_write(s, X[cur ^ 1], tid);

    // ---- P += Wl[16,FT] @ Vm[FT,256]; wave w owns e in [w*16, w*16+16) ----
#pragma unroll
    for (int ks = 0; ks < FT / 32; ++ks) {
      bf16x8_t a = *(const bf16x8_t*)&Wl[c16][ks * 32 + kb];
      const int e = w * 16 + c16;
      bf16x8_t bb;
#pragma unroll
      for (int i = 0; i < 8; ++i) {
        const int f = ks * 32 + kb + i;
        bb[i] = *(const __bf16*)(X[cur] + xoff(f, e << 1));
      }
      pacc = __builtin_amdgcn_mfma_f32_16x16x32_bf16(a, bb, pacc, 0, 0, 0);
    }
    __syncthreads();                       // PV + staging complete
    cur ^= 1;
  }

  // ---- write pooled partials [b][tb][q][e]; D[q][e]: q = g*4+r ----
  {
    const int e = w * 16 + c16;
#pragma unroll
    for (int r = 0; r < 4; ++r) {
      const int q = g * 4 + r;
      partials[(((size_t)b * NTB + tb) * Q_ + q) * E_ + e] = pacc[r];
    }
  }
}

// ---------------- tail: reduce + c-mapper (MFMA) + output projection --------
__global__ __launch_bounds__(TPB) __attribute__((amdgpu_waves_per_eu(4, 4)))
void tail_kernel(
    const float* __restrict__ partials, const unsigned short* __restrict__ WcT,
    const float* __restrict__ bc, const float* __restrict__ Wout,
    const float* __restrict__ bout, float* __restrict__ out) {
  const int blk = blockIdx.x;                 // rows [blk*64, blk*64+64) of B*Q
  const int tid = threadIdx.x;
  const int lane = tid & 63, w = tid >> 6;

  __shared__ __align__(128) char X[32768];
  __shared__ __align__(128) char Xt[32768];

  WFrag wf1, wf2;
  load_wfrag(wf1, WcT, w, lane);
  load_wfrag(wf2, WcT + 65536, w, lane);

  // ---- parallel reduce partials -> bf16 swizzled tile ----
#pragma unroll
  for (int j = 0; j < 2; ++j) {
    int u = j * 1024 + tid;
    int rl = u >> 5;
    int R = blk * 64 + rl;
    int b = R >> 4, q = R & 15;
    int e0 = (u & 31) << 3;
    f32x4 s0 = (f32x4){0.f, 0.f, 0.f, 0.f};
    f32x4 s1 = (f32x4){0.f, 0.f, 0.f, 0.f};
#pragma unroll
    for (int tb = 0; tb < NTB; ++tb) {
      const f32x4* p = (const f32x4*)(partials + (((size_t)(b * NTB + tb)) * Q_ + q) * E_ + e0);
      s0 += p[0];
      s1 += p[1];
    }
    bf16x8_t o;
    o[0] = (__bf16)s0[0]; o[1] = (__bf16)s0[1]; o[2] = (__bf16)s0[2]; o[3] = (__bf16)s0[3];
    o[4] = (__bf16)s1[0]; o[5] = (__bf16)s1[1]; o[6] = (__bf16)s1[2]; o[7] = (__bf16)s1[3];
    *(bf16x8_t*)(X + xoff(rl, e0 << 1)) = o;
  }
  __syncthreads();

  layer_res(X, Xt, wf1, bc, w, lane);
  layer_res(Xt, X, wf2, bc + E_, w, lane);

  // ---- out-proj: threads [0,512): row rl = tid>>3, label n = tid&7 ----
  if (tid < 512) {
    const int rl = tid >> 3, n = tid & 7;
    const int R = blk * 64 + rl;
    float sum = bout[n];
#pragma unroll
    for (int k0 = 0; k0 < E_; k0 += 8) {
      bf16x8_t h8 = *(const bf16x8_t*)(X + xoff(rl, k0 << 1));
#pragma unroll
      for (int i = 0; i < 8; ++i)
        sum += (float)h8[i] * Wout[(k0 + i) * NL_ + n];
    }
    out[R * NL_ + n] = sum;
  }
}

// ---------------- launch -----------------------------------------------------
extern "C" void kernel_launch(void* const* d_in, const int* in_sizes, int n_in,
                              void* d_out, int out_size, void* d_ws, size_t ws_size,
                              hipStream_t stream) {
  (void)in_sizes; (void)n_in; (void)out_size; (void)ws_size;
  const float* query    = (const float*)d_in[0];
  const float* features = (const float*)d_in[1];
  const float* values   = (const float*)d_in[2];
  const float* amask    = (const float*)d_in[3];
  const float* ftw      = (const float*)d_in[4];
  const float* Wq       = (const float*)d_in[5];
  const float* bq       = (const float*)d_in[6];
  const float* Wf       = (const float*)d_in[7];
  const float* bfb      = (const float*)d_in[8];
  const float* Wv       = (const float*)d_in[9];
  const float* bvb      = (const float*)d_in[10];
  const float* Wc       = (const float*)d_in[11];
  const float* bcb      = (const float*)d_in[12];
  const float* Wout     = (const float*)d_in[13];
  const float* bout     = (const float*)d_in[14];
  float* out = (float*)d_out;

  char* ws = (char*)d_ws;
  unsigned short* WtF = (unsigned short*)(ws);             // 256 KB
  unsigned short* WtV = (unsigned short*)(ws + 262144);    // 256 KB
  unsigned short* WqT = (unsigned short*)(ws + 524288);    // 256 KB
  unsigned short* WcT = (unsigned short*)(ws + 786432);    // 256 KB
  unsigned short* qmb = (unsigned short*)(ws + 1048576);   // 256 KB
  unsigned short* Wsg = (unsigned short*)(ws + 1310720);   // 4 MB
  float* partials     = (float*)(ws + 5505024);            // 4.2 MB

  prep_kernel<<<128, 256, 0, stream>>>(Wf, Wv, Wq, Wc, WtF, WtV, WqT, WcT);
  qmap_kernel<<<(B_ * Q_) / 64, TPB, 0, stream>>>(query, WqT, bq, qmb);
  passA_kernel<<<B_ * NTB, TPB, 0, stream>>>(features, amask, ftw,
                                             WtF, bfb, qmb, Wsg);
  passB_kernel<<<B_ * NTB, TPB, 0, stream>>>(values, WtV, bvb, Wsg, partials);
  tail_kernel<<<(B_ * Q_) / 64, TPB, 0, stream>>>(partials, WcT, bcb, Wout, bout, out);
}

// Round 15
// 232.026 us; speedup vs baseline: 1.2857x; 1.2857x over previous
//
#include <hip/hip_runtime.h>
#include <hip/hip_bf16.h>

// B=32, Q=16, F=4096, E=256, NL=8, L=2 residual layers per mapper.
#define B_   32
#define Q_   16
#define F_   4096
#define E_   256
#define NL_  8
#define FT   64     // feature rows per chunk
#define NTB  16     // row-tiles per batch (256 rows each)
#define CH   4      // chunks per tile (NTB*CH*FT == F_)
#define TPB  512    // 8 waves

typedef __attribute__((ext_vector_type(8))) __bf16 bf16x8_t;
typedef __attribute__((ext_vector_type(4))) __bf16 bf16x4_t;
typedef __attribute__((ext_vector_type(4))) float  f32x4;

// ---- LDS swizzle for [64][256] bf16 tiles (row stride 512 B) ----
__device__ __forceinline__ int swz(int r) {
  return ((r & 7) << 4) ^ (((r >> 3) & 3) << 5);
}
__device__ __forceinline__ int xoff(int r, int c2) {  // c2 = byte offset in row [0,512)
  return r * 512 + (c2 ^ swz(r));
}
__device__ __forceinline__ unsigned short f2bf_bits(float f) {
  __bf16 h = (__bf16)f;
  return __builtin_bit_cast(unsigned short, h);
}

// ---------------- prep: coalesced tiled transposes (8 mats, all bf16) -------
__global__ __launch_bounds__(256) void prep_kernel(
    const float* __restrict__ Wf, const float* __restrict__ Wv,
    const float* __restrict__ Wq, const float* __restrict__ Wc,
    unsigned short* __restrict__ WtF, unsigned short* __restrict__ WtV,
    unsigned short* __restrict__ WqT, unsigned short* __restrict__ WcT) {
  const int blk = blockIdx.x;
  const int t = threadIdx.x;
  __shared__ float ts[64][65];
  const int mat = blk >> 4;
  const int t16 = blk & 15;
  const int k0 = (t16 >> 2) * 64, n0 = (t16 & 3) * 64;
  const float* src;
  if (mat < 2) src = Wf + mat * 65536;
  else if (mat < 4) src = Wv + (mat - 2) * 65536;
  else if (mat < 6) src = Wq + (mat - 4) * 65536;
  else src = Wc + (mat - 6) * 65536;
#pragma unroll
  for (int p = 0; p < 16; ++p) {
    int e = p * 256 + t;
    int kk = e >> 6, nn = e & 63;
    ts[nn][kk] = src[(k0 + kk) * 256 + n0 + nn];   // coalesced in nn
  }
  __syncthreads();
  unsigned short* dst;
  if (mat < 2) dst = WtF + mat * 65536;
  else if (mat < 4) dst = WtV + (mat - 2) * 65536;
  else if (mat < 6) dst = WqT + (mat - 4) * 65536;
  else dst = WcT + (mat - 6) * 65536;
#pragma unroll
  for (int p = 0; p < 16; ++p) {
    int e = p * 256 + t;
    int nn = e >> 6, kk = e & 63;
    dst[(n0 + nn) * 256 + k0 + kk] = f2bf_bits(ts[nn][kk]);  // coalesced in kk
  }
}

// ---------------- staging: fp32 global -> bf16 swizzled LDS (immediate) -----
__device__ __forceinline__ void stage_tile(char* Xs, const float* __restrict__ src, int tid) {
  f32x4 v[8];
#pragma unroll
  for (int j = 0; j < 4; ++j) {
    int u = j * 512 + tid;                 // 16B-out-unit id (2048 per 64-row tile)
    int r = u >> 5;
    int c8 = (u & 31) << 3;
    const f32x4* p = (const f32x4*)(src + (size_t)r * E_ + c8);
    v[2 * j]     = __builtin_nontemporal_load(p);
    v[2 * j + 1] = __builtin_nontemporal_load(p + 1);
  }
#pragma unroll
  for (int j = 0; j < 4; ++j) {
    int u = j * 512 + tid;
    int r = u >> 5;
    int cb = (u & 31) << 4;
    f32x4 a = v[2 * j], b = v[2 * j + 1];
    bf16x8_t o;
    o[0] = (__bf16)a[0]; o[1] = (__bf16)a[1]; o[2] = (__bf16)a[2]; o[3] = (__bf16)a[3];
    o[4] = (__bf16)b[0]; o[5] = (__bf16)b[1]; o[6] = (__bf16)b[2]; o[7] = (__bf16)b[3];
    *(bf16x8_t*)(Xs + xoff(r, cb)) = o;
  }
}

// ---- In-place residual layer, L2-streamed weights (pinned preload). --------
// Wave w owns e in [w*32, w*32+32). D[e][m]. Two barriers: reads-done, writes-done.
__device__ __forceinline__ void layer_ip(char* __restrict__ X,
                                         const unsigned short* __restrict__ Wt,
                                         const float* __restrict__ bias, int w, int lane) {
  const int c16 = lane & 15, g = lane >> 4, kb = g << 3;
  const unsigned short* r0 = Wt + (w * 32 + c16) * E_ + kb;
  const unsigned short* r1 = Wt + (w * 32 + 16 + c16) * E_ + kb;

  // Preload all 16 weight fragments; sched_barrier(0) keeps the loads above
  // the MFMA loop (compiler would otherwise sink them to shrink pressure).
  bf16x8_t wa0[8], wa1[8];
#pragma unroll
  for (int ks = 0; ks < 8; ++ks) {
    wa0[ks] = *(const bf16x8_t*)(r0 + ks * 32);
    wa1[ks] = *(const bf16x8_t*)(r1 + ks * 32);
  }
  __builtin_amdgcn_sched_barrier(0);

  f32x4 acc[2][4];
#pragma unroll
  for (int ef = 0; ef < 2; ++ef)
#pragma unroll
    for (int mf = 0; mf < 4; ++mf) acc[ef][mf] = (f32x4){0.f, 0.f, 0.f, 0.f};

#pragma unroll
  for (int ks = 0; ks < 8; ++ks) {
    const int k = ks * 32 + kb;
#pragma unroll
    for (int mf = 0; mf < 4; ++mf) {
      bf16x8_t xb = *(const bf16x8_t*)(X + xoff(mf * 16 + c16, k << 1));
      acc[0][mf] = __builtin_amdgcn_mfma_f32_16x16x32_bf16(wa0[ks], xb, acc[0][mf], 0, 0, 0);
      acc[1][mf] = __builtin_amdgcn_mfma_f32_16x16x32_bf16(wa1[ks], xb, acc[1][mf], 0, 0, 0);
    }
  }
  __syncthreads();   // all waves' reads of X done before in-place writes
#pragma unroll
  for (int ef = 0; ef < 2; ++ef) {
    const int e0 = w * 32 + ef * 16 + (g << 2);
    const float4 b4 = *(const float4*)(bias + e0);
#pragma unroll
    for (int mf = 0; mf < 4; ++mf) {
      const int m = mf * 16 + c16;
      bf16x4_t* p = (bf16x4_t*)(X + xoff(m, e0 << 1));
      bf16x4_t old = *p;
      bf16x4_t nw;
      nw[0] = (__bf16)(fmaxf(acc[ef][mf][0] + b4.x, 0.f) + (float)old[0]);
      nw[1] = (__bf16)(fmaxf(acc[ef][mf][1] + b4.y, 0.f) + (float)old[1]);
      nw[2] = (__bf16)(fmaxf(acc[ef][mf][2] + b4.z, 0.f) + (float)old[2]);
      nw[3] = (__bf16)(fmaxf(acc[ef][mf][3] + b4.w, 0.f) + (float)old[3]);
      *p = nw;
    }
  }
  __syncthreads();
}

// ---------------- q-mapper via MFMA: 512 rows = B*Q, 8 blocks ---------------
__global__ __launch_bounds__(TPB) void qmap_kernel(
    const float* __restrict__ query, const unsigned short* __restrict__ WqT,
    const float* __restrict__ bq, unsigned short* __restrict__ qmb) {
  const int blk = blockIdx.x;                 // rows [blk*64, blk*64+64)
  const int tid = threadIdx.x;
  const int lane = tid & 63, w = tid >> 6;

  __shared__ __align__(128) char X[32768];

  stage_tile(X, query + (size_t)blk * 64 * E_, tid);
  __syncthreads();

  layer_ip(X, WqT, bq, w, lane);
  layer_ip(X, WqT + 65536, bq + E_, w, lane);

#pragma unroll
  for (int j = 0; j < 4; ++j) {
    int u = j * 512 + tid;
    int r = u >> 5;
    bf16x8_t v = *(const bf16x8_t*)(X + xoff(r, (u & 31) << 4));
    *(bf16x8_t*)(qmb + (size_t)(blk * 64 + r) * E_ + ((u & 31) << 3)) = v;
  }
}

// ---------------- pass A: features -> f-mapper -> S -> Ws -------------------
__global__ __launch_bounds__(TPB) void passA_kernel(
    const float* __restrict__ features,
    const float* __restrict__ amask, const float* __restrict__ ftw,
    const unsigned short* __restrict__ WtF, const float* __restrict__ bfb,
    const unsigned short* __restrict__ qmb, unsigned short* __restrict__ Wsg) {
  const int bid0 = blockIdx.x;
  const int bid = (bid0 & 7) * 64 + (bid0 >> 3);   // XCD swizzle (512 % 8 == 0)
  const int b = bid >> 4, tb = bid & 15;
  const int tid = threadIdx.x;
  const int lane = tid & 63, w = tid >> 6;
  const int c16 = lane & 15, g = lane >> 4, kb = g << 3;

  __shared__ __align__(128) char X[2][32768];   // 64 KB -> 2 blocks/CU

  const float* srcB = features + (size_t)(b * F_ + tb * CH * FT) * E_;

  stage_tile(X[0], srcB, tid);
  __syncthreads();
  int cur = 0;

  for (int c = 0; c < CH; ++c) {
    // stage next chunk into the dead buffer (immediate; TLP hides latency)
    if (c + 1 < CH) stage_tile(X[cur ^ 1], srcB + (size_t)(c + 1) * FT * E_, tid);

    layer_ip(X[cur], WtF, bfb, w, lane);             // 2 barriers inside
    layer_ip(X[cur], WtF + 65536, bfb + E_, w, lane);

    // ---- S = qm @ Fm^T (waves 0-3; wave w owns f rows [w*16, w*16+16)) ----
    if (w < 4) {
      const int f0 = (tb * CH + c) * FT;
      f32x4 sv = (f32x4){0.f, 0.f, 0.f, 0.f};
      const int fl = w * 16 + c16;
      const unsigned short* qbase = qmb + (size_t)(b * Q_ + c16) * E_ + kb;
#pragma unroll
      for (int ks = 0; ks < 8; ++ks) {
        bf16x8_t qa = *(const bf16x8_t*)(qbase + ks * 32);
        bf16x8_t xb = *(const bf16x8_t*)(X[cur] + xoff(fl, (ks * 32 + kb) << 1));
        sv = __builtin_amdgcn_mfma_f32_16x16x32_bf16(qa, xb, sv, 0, 0, 0);
      }
      const int fg = f0 + fl;
      const float lw = ftw[b * F_ + fg] * amask[b * F_ + fg];
#pragma unroll
      for (int r = 0; r < 4; ++r) {
        float sg = 1.f / (1.f + __expf(-sv[r]));
        Wsg[((size_t)(b * Q_ + g * 4 + r)) * F_ + fg] = f2bf_bits(sg * lw);
      }
    }
    __syncthreads();                       // staging + S complete
    cur ^= 1;
  }
}

// ---------------- pass B: values -> v-mapper -> PV -> partials --------------
__global__ __launch_bounds__(TPB) void passB_kernel(
    const float* __restrict__ values,
    const unsigned short* __restrict__ WtV, const float* __restrict__ bvb,
    const unsigned short* __restrict__ Wsg, float* __restrict__ partials) {
  const int bid0 = blockIdx.x;
  const int bid = (bid0 & 7) * 64 + (bid0 >> 3);
  const int b = bid >> 4, tb = bid & 15;
  const int tid = threadIdx.x;
  const int lane = tid & 63, w = tid >> 6;
  const int c16 = lane & 15, g = lane >> 4, kb = g << 3;

  __shared__ __align__(128) char X[2][32768];
  __shared__ __align__(16) unsigned short Wl[Q_][FT + 8];

  const float* srcB = values + (size_t)(b * F_ + tb * CH * FT) * E_;

  f32x4 pacc[2];
  pacc[0] = (f32x4){0.f, 0.f, 0.f, 0.f};
  pacc[1] = (f32x4){0.f, 0.f, 0.f, 0.f};

  stage_tile(X[0], srcB, tid);
  __syncthreads();
  int cur = 0;

  for (int c = 0; c < CH; ++c) {
    const int f0 = (tb * CH + c) * FT;
    if (c + 1 < CH) stage_tile(X[cur ^ 1], srcB + (size_t)(c + 1) * FT * E_, tid);

    layer_ip(X[cur], WtV, bvb, w, lane);             // 2 barriers inside

    // attn weights for this chunk (ordered before PV by layer2's barriers)
#pragma unroll
    for (int kk = 0; kk < 2; ++kk) {
      int idx = tid + kk * 512;              // 1024 = 16 q x 64 f
      int q = idx >> 6, j = idx & 63;
      Wl[q][j] = Wsg[((size_t)(b * Q_ + q)) * F_ + f0 + j];
    }

    layer_ip(X[cur], WtV + 65536, bvb + E_, w, lane);

    // ---- P += Wl[16,FT] @ Vm[FT,256]; wave w owns e in [w*32, w*32+32) ----
#pragma unroll
    for (int ks = 0; ks < FT / 32; ++ks) {
      bf16x8_t a = *(const bf16x8_t*)&Wl[c16][ks * 32 + kb];
#pragma unroll
      for (int nf = 0; nf < 2; ++nf) {
        const int e = w * 32 + nf * 16 + c16;
        bf16x8_t bb;
#pragma unroll
        for (int i = 0; i < 8; ++i) {
          const int f = ks * 32 + kb + i;
          bb[i] = *(const __bf16*)(X[cur] + xoff(f, e << 1));
        }
        pacc[nf] = __builtin_amdgcn_mfma_f32_16x16x32_bf16(a, bb, pacc[nf], 0, 0, 0);
      }
    }
    __syncthreads();                       // PV + staging complete
    cur ^= 1;
  }

  // ---- write pooled partials [b][tb][q][e]; D[q][e]: q = g*4+r ----
#pragma unroll
  for (int nf = 0; nf < 2; ++nf) {
    const int e = w * 32 + nf * 16 + c16;
#pragma unroll
    for (int r = 0; r < 4; ++r) {
      const int q = g * 4 + r;
      partials[(((size_t)b * NTB + tb) * Q_ + q) * E_ + e] = pacc[nf][r];
    }
  }
}

// ---------------- tail: reduce + c-mapper (MFMA) + output projection --------
__global__ __launch_bounds__(TPB) void tail_kernel(
    const float* __restrict__ partials, const unsigned short* __restrict__ WcT,
    const float* __restrict__ bc, const float* __restrict__ Wout,
    const float* __restrict__ bout, float* __restrict__ out) {
  const int blk = blockIdx.x;                 // rows [blk*64, blk*64+64) of B*Q
  const int tid = threadIdx.x;
  const int lane = tid & 63, w = tid >> 6;

  __shared__ __align__(128) char X[32768];

  // ---- parallel reduce partials -> bf16 swizzled tile ----
#pragma unroll
  for (int j = 0; j < 4; ++j) {
    int u = j * 512 + tid;
    int rl = u >> 5;
    int R = blk * 64 + rl;
    int b = R >> 4, q = R & 15;
    int e0 = (u & 31) << 3;
    f32x4 s0 = (f32x4){0.f, 0.f, 0.f, 0.f};
    f32x4 s1 = (f32x4){0.f, 0.f, 0.f, 0.f};
#pragma unroll
    for (int tb = 0; tb < NTB; ++tb) {
      const f32x4* p = (const f32x4*)(partials + (((size_t)(b * NTB + tb)) * Q_ + q) * E_ + e0);
      s0 += p[0];
      s1 += p[1];
    }
    bf16x8_t o;
    o[0] = (__bf16)s0[0]; o[1] = (__bf16)s0[1]; o[2] = (__bf16)s0[2]; o[3] = (__bf16)s0[3];
    o[4] = (__bf16)s1[0]; o[5] = (__bf16)s1[1]; o[6] = (__bf16)s1[2]; o[7] = (__bf16)s1[3];
    *(bf16x8_t*)(X + xoff(rl, e0 << 1)) = o;
  }
  __syncthreads();

  layer_ip(X, WcT, bc, w, lane);
  layer_ip(X, WcT + 65536, bc + E_, w, lane);

  // ---- out-proj: thread -> (row rl = tid>>3, label n = tid&7) ----
  {
    const int rl = tid >> 3, n = tid & 7;
    const int R = blk * 64 + rl;
    float sum = bout[n];
#pragma unroll
    for (int k0 = 0; k0 < E_; k0 += 8) {
      bf16x8_t h8 = *(const bf16x8_t*)(X + xoff(rl, k0 << 1));
#pragma unroll
      for (int i = 0; i < 8; ++i)
        sum += (float)h8[i] * Wout[(k0 + i) * NL_ + n];
    }
    out[R * NL_ + n] = sum;
  }
}

// ---------------- launch -----------------------------------------------------
extern "C" void kernel_launch(void* const* d_in, const int* in_sizes, int n_in,
                              void* d_out, int out_size, void* d_ws, size_t ws_size,
                              hipStream_t stream) {
  (void)in_sizes; (void)n_in; (void)out_size; (void)ws_size;
  const float* query    = (const float*)d_in[0];
  const float* features = (const float*)d_in[1];
  const float* values   = (const float*)d_in[2];
  const float* amask    = (const float*)d_in[3];
  const float* ftw      = (const float*)d_in[4];
  const float* Wq       = (const float*)d_in[5];
  const float* bq       = (const float*)d_in[6];
  const float* Wf       = (const float*)d_in[7];
  const float* bfb      = (const float*)d_in[8];
  const float* Wv       = (const float*)d_in[9];
  const float* bvb      = (const float*)d_in[10];
  const float* Wc       = (const float*)d_in[11];
  const float* bcb      = (const float*)d_in[12];
  const float* Wout     = (const float*)d_in[13];
  const float* bout     = (const float*)d_in[14];
  float* out = (float*)d_out;

  char* ws = (char*)d_ws;
  unsigned short* WtF = (unsigned short*)(ws);             // 256 KB
  unsigned short* WtV = (unsigned short*)(ws + 262144);    // 256 KB
  unsigned short* WqT = (unsigned short*)(ws + 524288);    // 256 KB
  unsigned short* WcT = (unsigned short*)(ws + 786432);    // 256 KB
  unsigned short* qmb = (unsigned short*)(ws + 1048576);   // 256 KB
  unsigned short* Wsg = (unsigned short*)(ws + 1310720);   // 4 MB
  float* partials     = (float*)(ws + 5505024);            // 8.4 MB

  prep_kernel<<<128, 256, 0, stream>>>(Wf, Wv, Wq, Wc, WtF, WtV, WqT, WcT);
  qmap_kernel<<<(B_ * Q_) / 64, TPB, 0, stream>>>(query, WqT, bq, qmb);
  passA_kernel<<<B_ * NTB, TPB, 0, stream>>>(features, amask, ftw,
                                             WtF, bfb, qmb, Wsg);
  passB_kernel<<<B_ * NTB, TPB, 0, stream>>>(values, WtV, bvb, Wsg, partials);
  tail_kernel<<<(B_ * Q_) / 64, TPB, 0, stream>>>(partials, WcT, bcb, Wout, bout, out);
}